// Round 22
// baseline (109.111 us; speedup 1.0000x reference)
//
#include <hip/hip_runtime.h>
#include <stdint.h>

#define B_ 2
#define T_ 2048
#define C_ 1024
#define H_ 16
#define D_ 64
// SCALE * log2(e): softmax computed in exp2 domain; folded into Q at rope time
#define SCALE_L2E 0.1803368801111244f

typedef unsigned short ushort_t;
typedef __attribute__((ext_vector_type(8))) __bf16 bf16x8;
typedef __attribute__((ext_vector_type(4))) float f32x4;
typedef __attribute__((ext_vector_type(4))) unsigned short ushort4_t;

__device__ __forceinline__ float bf2f(ushort_t u) {
    union { unsigned int u; float f; } v; v.u = ((unsigned int)u) << 16; return v.f;
}
__device__ __forceinline__ ushort_t f2bf(float f) {
    union { __bf16 h; ushort_t u; } v; v.h = (__bf16)f; return v.u;
}
__device__ __forceinline__ float fexp2(float x) { return __builtin_amdgcn_exp2f(x); }

__device__ __forceinline__ void gl16(const void* g, void* l) {
    __builtin_amdgcn_global_load_lds(
        (const __attribute__((address_space(1))) void*)g,
        (__attribute__((address_space(3))) void*)l, 16, 0, 0);
}

__device__ __forceinline__ f32x4 mfma16(bf16x8 a, bf16x8 b, f32x4 c) {
    return __builtin_amdgcn_mfma_f32_16x16x32_bf16(a, b, c, 0, 0, 0);
}

// ---------------- fused fp32 -> bf16 convert (3 tensors) ----------------
__global__ __launch_bounds__(256) void cvt3_kernel(const float* __restrict__ a, ushort_t* __restrict__ oa, int na,
                                                   const float* __restrict__ b, ushort_t* __restrict__ ob, int nb,
                                                   const float* __restrict__ c, ushort_t* __restrict__ oc, int nc) {
    int total4 = (na + nb + nc) >> 2;
    int stride = gridDim.x * blockDim.x;
    for (int i = blockIdx.x * blockDim.x + threadIdx.x; i < total4; i += stride) {
        int e = i << 2;
        const float* src; ushort_t* dst; int off;
        if (e < na) { src = a; dst = oa; off = e; }
        else if (e < na + nb) { src = b; dst = ob; off = e - na; }
        else { src = c; dst = oc; off = e - na - nb; }
        float4 v = *(const float4*)(src + off);
        ushort4_t o;
        o.x = f2bf(v.x); o.y = f2bf(v.y); o.z = f2bf(v.z); o.w = f2bf(v.w);
        *(ushort4_t*)(dst + off) = o;
    }
}

// ---------------- GEMM (proj): 64x128 tile, PAIRED K-steps (quad-buffer) ----------------
__global__ __launch_bounds__(256) void gemm_proj(const ushort_t* __restrict__ A,
                                                 const ushort_t* __restrict__ Bw,
                                                 const float* __restrict__ bias,
                                                 float* __restrict__ outf,
                                                 int M, int N, int K, int nxt) {
    int q = gridDim.x >> 3;
    int nid = (blockIdx.x & 7) * q + (blockIdx.x >> 3);
    int bx = nid % nxt, by = nid / nxt;

    __shared__ ushort_t sm[24576];   // 4 bufs x (As 2048 + Bs 4096) elems
    int tid = threadIdx.x, w = tid >> 6, lane = tid & 63;
    int lr = lane >> 4, lc = lane & 15;
    int wr = w >> 1, wc = w & 1;
    int row0 = by * 64, col0 = bx * 128;

    f32x4 acc[2][4];
#pragma unroll
    for (int mf = 0; mf < 2; ++mf)
#pragma unroll
        for (int nf = 0; nf < 4; ++nf) acc[mf][nf] = (f32x4){0.f, 0.f, 0.f, 0.f};

    auto stageg = [&](int buf, int k0) {
        int base = buf * 6144;
        int rA = tid >> 2, cA = (tid & 3) * 8;
        gl16(A + (size_t)(row0 + rA) * K + k0 + cA, &sm[base + tid * 8]);
#pragma unroll
        for (int j = 0; j < 2; ++j) {
            int idx = j * 256 + tid;
            int rB = idx >> 2, cB = (idx & 3) * 8;
            gl16(Bw + (size_t)(col0 + rB) * K + k0 + cB, &sm[base + 2048 + idx * 8]);
        }
    };

    stageg(0, 0);
    stageg(1, 32);
    asm volatile("s_waitcnt vmcnt(0)" ::: "memory");
    __builtin_amdgcn_s_barrier();

    for (int k0 = 0; k0 < K; k0 += 64) {
        int ps = (k0 >> 6) & 1;
        bool st = (k0 + 64 < K);
        if (st) {
            stageg((ps ^ 1) * 2, k0 + 64);
            stageg((ps ^ 1) * 2 + 1, k0 + 96);
        }
#pragma unroll
        for (int s = 0; s < 2; ++s) {
            const ushort_t* As = &sm[(ps * 2 + s) * 6144];
            const ushort_t* Bs = As + 2048;
            bf16x8 af[2], bfr[4];
#pragma unroll
            for (int mf = 0; mf < 2; ++mf)
                af[mf] = *(const bf16x8*)&As[(wr * 32 + mf * 16 + lc) * 32 + 8 * lr];
#pragma unroll
            for (int nf = 0; nf < 4; ++nf)
                bfr[nf] = *(const bf16x8*)&Bs[(wc * 64 + nf * 16 + lc) * 32 + 8 * lr];
            __builtin_amdgcn_s_setprio(1);
#pragma unroll
            for (int mf = 0; mf < 2; ++mf)
#pragma unroll
                for (int nf = 0; nf < 4; ++nf)
                    acc[mf][nf] = mfma16(af[mf], bfr[nf], acc[mf][nf]);
            __builtin_amdgcn_s_setprio(0);
        }
        asm volatile("s_waitcnt vmcnt(0)" ::: "memory");
        __builtin_amdgcn_s_barrier();
    }
#pragma unroll
    for (int mf = 0; mf < 2; ++mf)
#pragma unroll
        for (int nf = 0; nf < 4; ++nf) {
            int col = col0 + wc * 64 + nf * 16 + lc;
            float bv = bias[col];
#pragma unroll
            for (int r = 0; r < 4; ++r) {
                int row = row0 + wr * 32 + mf * 16 + 4 * lr + r;
                outf[(size_t)row * N + col] = acc[mf][nf][r] + bv;
            }
        }
}

// ---------------- GEMM1 fused: QKV + RoPE + scatter, PAIRED K-steps (quad-buffer) ----------------
__global__ __launch_bounds__(256) void gemm_qkv_rope(const ushort_t* __restrict__ A,
                                                     const ushort_t* __restrict__ Bw,
                                                     const float* __restrict__ bias,
                                                     const float* __restrict__ cosT,
                                                     const float* __restrict__ sinT,
                                                     ushort_t* __restrict__ Qr,
                                                     ushort_t* __restrict__ Kr,
                                                     ushort_t* __restrict__ Vt) {
    const int K = 1024;
    int x = blockIdx.x & 7;            // XCD
    int local = blockIdx.x >> 3;       // 0..95
    int band = x >> 1;
    int half = x & 1;
    int by = band * 8 + (local & 7);
    int bx = half * 12 + (local >> 3);

    __shared__ ushort_t sm[32768];   // 4 bufs; aliased for V-transpose
    int tid = threadIdx.x, w = tid >> 6, lane = tid & 63;
    int lr = lane >> 4, lc = lane & 15;
    int wr = w >> 1, wc = w & 1;
    int row0 = by * 128, col0 = bx * 128;

    f32x4 acc[4][4];
#pragma unroll
    for (int mf = 0; mf < 4; ++mf)
#pragma unroll
        for (int nf = 0; nf < 4; ++nf) acc[mf][nf] = (f32x4){0.f, 0.f, 0.f, 0.f};

    auto stageg = [&](int buf, int k0) {
#pragma unroll
        for (int j = 0; j < 2; ++j) {
            int idx = j * 256 + tid;
            int r = idx >> 2, c = (idx & 3) * 8;
            gl16(A + (size_t)(row0 + r) * K + k0 + c, &sm[buf * 8192 + idx * 8]);
            gl16(Bw + (size_t)(col0 + r) * K + k0 + c, &sm[buf * 8192 + 4096 + idx * 8]);
        }
    };

    stageg(0, 0);
    stageg(1, 32);
    asm volatile("s_waitcnt vmcnt(0)" ::: "memory");
    __builtin_amdgcn_s_barrier();

    for (int k0 = 0; k0 < K; k0 += 64) {
        int ps = (k0 >> 6) & 1;
        bool st = (k0 + 64 < K);
        if (st) {
            stageg((ps ^ 1) * 2, k0 + 64);
            stageg((ps ^ 1) * 2 + 1, k0 + 96);
        }
#pragma unroll
        for (int s = 0; s < 2; ++s) {
            const ushort_t* As = &sm[(ps * 2 + s) * 8192];
            const ushort_t* Bs = As + 4096;
            bf16x8 af[4], bfr[4];
#pragma unroll
            for (int mf = 0; mf < 4; ++mf)
                af[mf] = *(const bf16x8*)&As[(wr * 64 + mf * 16 + lc) * 32 + 8 * lr];
#pragma unroll
            for (int nf = 0; nf < 4; ++nf)
                bfr[nf] = *(const bf16x8*)&Bs[(wc * 64 + nf * 16 + lc) * 32 + 8 * lr];
            __builtin_amdgcn_s_setprio(1);
#pragma unroll
            for (int mf = 0; mf < 4; ++mf)
#pragma unroll
                for (int nf = 0; nf < 4; ++nf)
                    acc[mf][nf] = mfma16(af[mf], bfr[nf], acc[mf][nf]);
            __builtin_amdgcn_s_setprio(0);
        }
        asm volatile("s_waitcnt vmcnt(0)" ::: "memory");
        __builtin_amdgcn_s_barrier();
    }

    if (bx < 16) {
        // ---- Q / K epilogue with RoPE ----
        const int typ = bx >> 3;                 // 0 = Q, 1 = K
        ushort_t* dstb = typ ? Kr : Qr;
#pragma unroll
        for (int nf = 0; nf < 4; ++nf) {
            int fullc = col0 + wc * 64 + nf * 16 + lc;
            int gc = fullc & 1023;
            int h = gc >> 6;
            int d2 = (gc & 63) >> 1;
            int odd = gc & 1;
            float bv = bias[fullc];
#pragma unroll
            for (int mf = 0; mf < 4; ++mf)
#pragma unroll
                for (int r = 0; r < 4; ++r) {
                    int row = row0 + wr * 64 + mf * 16 + 4 * lr + r;
                    int bb = row >> 11, t = row & 2047;
                    float v = acc[mf][nf][r] + bv;
                    float pv = __shfl_xor(v, 1, 64);
                    float cth = cosT[t * 32 + d2], sth = sinT[t * 32 + d2];
                    float o = odd ? (pv * sth + v * cth) : (v * cth - pv * sth);
                    if (typ == 0) o *= SCALE_L2E;
                    int od = odd ? (d2 + 32) : d2;
                    dstb[((size_t)(bb * H_ + h) * T_ + t) * D_ + od] = f2bf(o);
                }
        }
    } else {
        // ---- V epilogue: transpose 128t x 64c half-tiles through LDS ----
        int bb = row0 >> 11;
        int tb = row0 & 2047;
#pragma unroll 1
        for (int half2 = 0; half2 < 2; ++half2) {
            __syncthreads();
            if (wc == half2) {
#pragma unroll
                for (int nf = 0; nf < 4; ++nf) {
                    int fullc = col0 + wc * 64 + nf * 16 + lc;
                    float bv = bias[fullc];
                    int c = nf * 16 + lc;
#pragma unroll
                    for (int mf = 0; mf < 4; ++mf)
#pragma unroll
                        for (int r = 0; r < 4; ++r) {
                            int tl = wr * 64 + mf * 16 + 4 * lr + r;
                            sm[c * 136 + tl] = f2bf(acc[mf][nf][r] + bv);
                        }
                }
            }
            __syncthreads();
            int h = ((bx - 16) << 1) + half2;
#pragma unroll
            for (int it = 0; it < 8; ++it) {
                int idx = it * 256 + tid;
                int c = idx >> 5, j = idx & 31;
                ushort4_t vv = *(const ushort4_t*)&sm[c * 136 + 4 * j];
                *(ushort4_t*)&Vt[((size_t)(bb * H_ + h) * D_ + c) * T_ + tb + 4 * j] = vv;
            }
        }
    }
}

// ---------------- causal flash attention: 32 KB LDS (V single-buffered), 5 blocks/CU ----------------
// Static quartet mapping (bh XCD-affine). Entire 1024-block grid co-resident:
// K dbuf + V single; per-iter: {vmcnt0+bar (K-gate) | issue V(kt),K(kt+1) | QK |
// softmax | vmcnt2+bar (V-gate, K in flight) | PV}.
__global__ __launch_bounds__(256) void attn_kernel(const ushort_t* __restrict__ Qr,
                                                   const ushort_t* __restrict__ Kr,
                                                   const ushort_t* __restrict__ Vt,
                                                   ushort_t* __restrict__ attnb) {
    int id = blockIdx.x;
    int x = id & 7;
    int c = (id >> 3) & 31;
    int g = id >> 8;               // 0..3
    int bh = x + 8 * g;
    int qt;
    if (g == 0) qt = c;
    else if (g == 1) qt = 31 - c;
    else if (g == 2) qt = (c + 16) & 31;
    else qt = 31 - ((c + 16) & 31);
    int b = bh >> 4, h = bh & 15;

    const ushort_t* Qp = Qr + (size_t)bh * T_ * D_;
    const ushort_t* Kp = Kr + (size_t)bh * T_ * D_;
    const ushort_t* Vp = Vt + (size_t)bh * D_ * T_;
    int tid = threadIdx.x, w = tid >> 6, lane = tid & 63;
    int lr = lane >> 4, lc = lane & 15;

    __shared__ ushort_t Ks[2][64 * 64];   // 16 KB
    __shared__ ushort_t Vs[64 * 64];      //  8 KB
    __shared__ ushort_t Ps[4][16 * 64];   //  8 KB

    bf16x8 ones;
#pragma unroll
    for (int i = 0; i < 8; ++i) ones[i] = (__bf16)1.0f;

    int srow0 = tid >> 3, sch0 = (tid & 7) ^ (srow0 & 7);
    int srow1 = (256 + tid) >> 3, sch1 = (tid & 7) ^ (srow1 & 7);
    const ushort_t* kg0 = Kp + (size_t)srow0 * D_ + sch0 * 8;
    const ushort_t* kg1 = Kp + (size_t)srow1 * D_ + sch1 * 8;
    const ushort_t* vg0 = Vp + (size_t)srow0 * T_ + sch0 * 8;
    const ushort_t* vg1 = Vp + (size_t)srow1 * T_ + sch1 * 8;
    ushort_t* kl0 = &Ks[0][tid * 8];
    ushort_t* kl1 = &Ks[0][(256 + tid) * 8];
    ushort_t* vl0 = &Vs[tid * 8];
    ushort_t* vl1 = &Vs[(256 + tid) * 8];

    auto stageK = [&](int buf, int kt) {
        size_t koff = (size_t)kt * 64 * D_;
        size_t lb = (size_t)buf * 4096;
        gl16(kg0 + koff, kl0 + lb);
        gl16(kg1 + koff, kl1 + lb);
    };
    auto stageV = [&](int kt) {
        size_t voff = (size_t)kt * 64;
        gl16(vg0 + voff, vl0);
        gl16(vg1 + voff, vl1);
    };

    int qrow = qt * 64 + w * 16 + lc;
    bf16x8 qf0 = *(const bf16x8*)(Qp + (size_t)qrow * D_ + 8 * lr);
    bf16x8 qf1 = *(const bf16x8*)(Qp + (size_t)qrow * D_ + 32 + 8 * lr);

    float m_s = 0.f;
    f32x4 acc[4], acc_l;
#pragma unroll
    for (int f = 0; f < 4; ++f) acc[f] = (f32x4){0.f, 0.f, 0.f, 0.f};
    acc_l = (f32x4){0.f, 0.f, 0.f, 0.f};

    stageK(0, 0);

    for (int kt = 0; kt <= qt; ++kt) {
        int cur = kt & 1;
        int t0 = kt * 64;
        // K-gate: K(kt), issued a full iteration ago (or prologue), must land.
        // Also: all waves finished prev iter's PV -> safe to overwrite Vs.
        asm volatile("s_waitcnt vmcnt(0)" ::: "memory");
        __builtin_amdgcn_s_barrier();
        stageV(kt);
        if (kt < qt) stageK(cur ^ 1, kt + 1);

        f32x4 sv[4];
        __builtin_amdgcn_s_setprio(1);
#pragma unroll
        for (int f = 0; f < 4; ++f) {
            sv[f] = (f32x4){-m_s, -m_s, -m_s, -m_s};
            int row = 16 * f + lc;
#pragma unroll
            for (int kk = 0; kk < 2; ++kk) {
                bf16x8 kf = *(const bf16x8*)&Ks[cur][row * 64 + (((lr + 4 * kk) ^ (row & 7)) * 8)];
                sv[f] = mfma16(kf, kk ? qf1 : qf0, sv[f]);
            }
        }
        __builtin_amdgcn_s_setprio(0);

        float lm = -1e30f;
        if (kt == qt) {
#pragma unroll
            for (int f = 0; f < 4; ++f)
#pragma unroll
                for (int r = 0; r < 4; ++r) {
                    int kg = t0 + 16 * f + 4 * lr + r;
                    float v = sv[f][r];
                    v = (kg > qrow) ? -1e30f : v;
                    sv[f][r] = v;
                    lm = fmaxf(lm, v);
                }
        } else {
#pragma unroll
            for (int f = 0; f < 4; ++f)
#pragma unroll
                for (int r = 0; r < 4; ++r)
                    lm = fmaxf(lm, sv[f][r]);
        }

        if (!__all(lm <= 8.0f)) {
            float tm = fmaxf(lm, __shfl_xor(lm, 16, 64));
            tm = fmaxf(tm, __shfl_xor(tm, 32, 64));
            float d = fmaxf(tm, 0.f);
            m_s += d;
            float alpha = fexp2(-d);
            float ar[4];
#pragma unroll
            for (int r = 0; r < 4; ++r) ar[r] = __shfl(alpha, 4 * lr + r, 64);
#pragma unroll
            for (int r = 0; r < 4; ++r) {
                acc_l[r] *= ar[r];
#pragma unroll
                for (int f = 0; f < 4; ++f) acc[f][r] *= ar[r];
            }
#pragma unroll
            for (int f = 0; f < 4; ++f)
#pragma unroll
                for (int r = 0; r < 4; ++r) sv[f][r] -= d;
        }

#pragma unroll
        for (int f = 0; f < 4; ++f) {
            ushort4_t pk;
            pk.x = f2bf(fexp2(sv[f][0]));
            pk.y = f2bf(fexp2(sv[f][1]));
            pk.z = f2bf(fexp2(sv[f][2]));
            pk.w = f2bf(fexp2(sv[f][3]));
            *(ushort4_t*)&Ps[w][lc * 64 + (((4 * f + lr) ^ (lc & 14)) << 2)] = pk;
        }

        // V-gate: V(kt) landed; K(kt+1)'s 2 loads stay in flight
        if (kt < qt) {
            asm volatile("s_waitcnt vmcnt(2)" ::: "memory");
        } else {
            asm volatile("s_waitcnt vmcnt(0)" ::: "memory");
        }
        __builtin_amdgcn_s_barrier();

        __builtin_amdgcn_s_setprio(1);
#pragma unroll
        for (int kk = 0; kk < 2; ++kk) {
            bf16x8 pf = *(const bf16x8*)&Ps[w][lc * 64 + (((8 * kk + 2 * lr) ^ (lc & 14)) << 2)];
            acc_l = mfma16(pf, ones, acc_l);
#pragma unroll
            for (int f = 0; f < 4; ++f) {
                int vrow = 16 * f + lc;
                bf16x8 vfr = *(const bf16x8*)&Vs[vrow * 64 + (((lr + 4 * kk) ^ (vrow & 7)) * 8)];
                acc[f] = mfma16(pf, vfr, acc[f]);
            }
        }
        __builtin_amdgcn_s_setprio(0);
    }

    float inv[4];
#pragma unroll
    for (int r = 0; r < 4; ++r) inv[r] = __builtin_amdgcn_rcpf(acc_l[r]);
#pragma unroll
    for (int f = 0; f < 4; ++f)
#pragma unroll
        for (int r = 0; r < 4; ++r) {
            int t = qt * 64 + w * 16 + 4 * lr + r;
            attnb[((size_t)(b * T_ + t)) * 1024 + h * 64 + 16 * f + lc] =
                f2bf(acc[f][r] * inv[r]);
        }
}

extern "C" void kernel_launch(void* const* d_in, const int* in_sizes, int n_in,
                              void* d_out, int out_size, void* d_ws, size_t ws_size,
                              hipStream_t stream) {
    const float* hs     = (const float*)d_in[0];
    const float* cosp   = (const float*)d_in[1];
    const float* sinp   = (const float*)d_in[2];
    const float* qkv_w  = (const float*)d_in[3];
    const float* qkv_b  = (const float*)d_in[4];
    const float* proj_w = (const float*)d_in[5];
    const float* proj_b = (const float*)d_in[6];
    float* out = (float*)d_out;

    const int M = B_ * T_;            // 4096
    ushort_t* Xb     = (ushort_t*)d_ws;
    ushort_t* Wqkvb  = Xb + (size_t)M * C_;
    ushort_t* Wprojb = Wqkvb + (size_t)3072 * C_;
    ushort_t* Qr     = Wprojb + (size_t)C_ * C_;
    ushort_t* Kr     = Qr + (size_t)B_ * H_ * T_ * D_;
    ushort_t* Vt     = Kr + (size_t)B_ * H_ * T_ * D_;
    ushort_t* attnb  = Vt + (size_t)B_ * H_ * T_ * D_;

    cvt3_kernel<<<2048, 256, 0, stream>>>(hs, Xb, M * C_,
                                          qkv_w, Wqkvb, 3072 * C_,
                                          proj_w, Wprojb, C_ * C_);

    gemm_qkv_rope<<<768, 256, 0, stream>>>(Xb, Wqkvb, qkv_b, cosp, sinp, Qr, Kr, Vt);

    attn_kernel<<<1024, 256, 0, stream>>>(Qr, Kr, Vt, attnb);

    gemm_proj<<<512, 256, 0, stream>>>(attnb, Wprojb, proj_b, out, M, C_, C_, 8);
}

// Round 23
// 107.234 us; speedup vs baseline: 1.0175x; 1.0175x over previous
//
#include <hip/hip_runtime.h>
#include <stdint.h>

#define B_ 2
#define T_ 2048
#define C_ 1024
#define H_ 16
#define D_ 64
// SCALE * log2(e): softmax computed in exp2 domain; folded into Q at rope time
#define SCALE_L2E 0.1803368801111244f

typedef unsigned short ushort_t;
typedef __attribute__((ext_vector_type(8))) __bf16 bf16x8;
typedef __attribute__((ext_vector_type(4))) float f32x4;
typedef __attribute__((ext_vector_type(4))) unsigned short ushort4_t;

__device__ __forceinline__ float bf2f(ushort_t u) {
    union { unsigned int u; float f; } v; v.u = ((unsigned int)u) << 16; return v.f;
}
__device__ __forceinline__ ushort_t f2bf(float f) {
    union { __bf16 h; ushort_t u; } v; v.h = (__bf16)f; return v.u;
}
__device__ __forceinline__ float fexp2(float x) { return __builtin_amdgcn_exp2f(x); }

__device__ __forceinline__ void gl16(const void* g, void* l) {
    __builtin_amdgcn_global_load_lds(
        (const __attribute__((address_space(1))) void*)g,
        (__attribute__((address_space(3))) void*)l, 16, 0, 0);
}

__device__ __forceinline__ f32x4 mfma16(bf16x8 a, bf16x8 b, f32x4 c) {
    return __builtin_amdgcn_mfma_f32_16x16x32_bf16(a, b, c, 0, 0, 0);
}

// ---------------- fused fp32 -> bf16 convert (3 tensors) ----------------
__global__ __launch_bounds__(256) void cvt3_kernel(const float* __restrict__ a, ushort_t* __restrict__ oa, int na,
                                                   const float* __restrict__ b, ushort_t* __restrict__ ob, int nb,
                                                   const float* __restrict__ c, ushort_t* __restrict__ oc, int nc) {
    int total4 = (na + nb + nc) >> 2;
    int stride = gridDim.x * blockDim.x;
    for (int i = blockIdx.x * blockDim.x + threadIdx.x; i < total4; i += stride) {
        int e = i << 2;
        const float* src; ushort_t* dst; int off;
        if (e < na) { src = a; dst = oa; off = e; }
        else if (e < na + nb) { src = b; dst = ob; off = e - na; }
        else { src = c; dst = oc; off = e - na - nb; }
        float4 v = *(const float4*)(src + off);
        ushort4_t o;
        o.x = f2bf(v.x); o.y = f2bf(v.y); o.z = f2bf(v.z); o.w = f2bf(v.w);
        *(ushort4_t*)(dst + off) = o;
    }
}

// ---------------- GEMM (proj): 64x128 tile, PAIRED K-steps (quad-buffer) ----------------
__global__ __launch_bounds__(256) void gemm_proj(const ushort_t* __restrict__ A,
                                                 const ushort_t* __restrict__ Bw,
                                                 const float* __restrict__ bias,
                                                 float* __restrict__ outf,
                                                 int M, int N, int K, int nxt) {
    int q = gridDim.x >> 3;
    int nid = (blockIdx.x & 7) * q + (blockIdx.x >> 3);
    int bx = nid % nxt, by = nid / nxt;

    __shared__ ushort_t sm[24576];   // 4 bufs x (As 2048 + Bs 4096) elems
    int tid = threadIdx.x, w = tid >> 6, lane = tid & 63;
    int lr = lane >> 4, lc = lane & 15;
    int wr = w >> 1, wc = w & 1;
    int row0 = by * 64, col0 = bx * 128;

    f32x4 acc[2][4];
#pragma unroll
    for (int mf = 0; mf < 2; ++mf)
#pragma unroll
        for (int nf = 0; nf < 4; ++nf) acc[mf][nf] = (f32x4){0.f, 0.f, 0.f, 0.f};

    auto stageg = [&](int buf, int k0) {
        int base = buf * 6144;
        int rA = tid >> 2, cA = (tid & 3) * 8;
        gl16(A + (size_t)(row0 + rA) * K + k0 + cA, &sm[base + tid * 8]);
#pragma unroll
        for (int j = 0; j < 2; ++j) {
            int idx = j * 256 + tid;
            int rB = idx >> 2, cB = (idx & 3) * 8;
            gl16(Bw + (size_t)(col0 + rB) * K + k0 + cB, &sm[base + 2048 + idx * 8]);
        }
    };

    stageg(0, 0);
    stageg(1, 32);
    asm volatile("s_waitcnt vmcnt(0)" ::: "memory");
    __builtin_amdgcn_s_barrier();

    for (int k0 = 0; k0 < K; k0 += 64) {
        int ps = (k0 >> 6) & 1;
        bool st = (k0 + 64 < K);
        if (st) {
            stageg((ps ^ 1) * 2, k0 + 64);
            stageg((ps ^ 1) * 2 + 1, k0 + 96);
        }
#pragma unroll
        for (int s = 0; s < 2; ++s) {
            const ushort_t* As = &sm[(ps * 2 + s) * 6144];
            const ushort_t* Bs = As + 2048;
            bf16x8 af[2], bfr[4];
#pragma unroll
            for (int mf = 0; mf < 2; ++mf)
                af[mf] = *(const bf16x8*)&As[(wr * 32 + mf * 16 + lc) * 32 + 8 * lr];
#pragma unroll
            for (int nf = 0; nf < 4; ++nf)
                bfr[nf] = *(const bf16x8*)&Bs[(wc * 64 + nf * 16 + lc) * 32 + 8 * lr];
            __builtin_amdgcn_s_setprio(1);
#pragma unroll
            for (int mf = 0; mf < 2; ++mf)
#pragma unroll
                for (int nf = 0; nf < 4; ++nf)
                    acc[mf][nf] = mfma16(af[mf], bfr[nf], acc[mf][nf]);
            __builtin_amdgcn_s_setprio(0);
        }
        asm volatile("s_waitcnt vmcnt(0)" ::: "memory");
        __builtin_amdgcn_s_barrier();
    }
#pragma unroll
    for (int mf = 0; mf < 2; ++mf)
#pragma unroll
        for (int nf = 0; nf < 4; ++nf) {
            int col = col0 + wc * 64 + nf * 16 + lc;
            float bv = bias[col];
#pragma unroll
            for (int r = 0; r < 4; ++r) {
                int row = row0 + wr * 32 + mf * 16 + 4 * lr + r;
                outf[(size_t)row * N + col] = acc[mf][nf][r] + bv;
            }
        }
}

// ---------------- GEMM1 fused: QKV + RoPE + scatter, PAIRED K-steps (quad-buffer) ----------------
__global__ __launch_bounds__(256) void gemm_qkv_rope(const ushort_t* __restrict__ A,
                                                     const ushort_t* __restrict__ Bw,
                                                     const float* __restrict__ bias,
                                                     const float* __restrict__ cosT,
                                                     const float* __restrict__ sinT,
                                                     ushort_t* __restrict__ Qr,
                                                     ushort_t* __restrict__ Kr,
                                                     ushort_t* __restrict__ Vt) {
    const int K = 1024;
    int x = blockIdx.x & 7;            // XCD
    int local = blockIdx.x >> 3;       // 0..95
    int band = x >> 1;
    int half = x & 1;
    int by = band * 8 + (local & 7);
    int bx = half * 12 + (local >> 3);

    __shared__ ushort_t sm[32768];   // 4 bufs; aliased for V-transpose
    int tid = threadIdx.x, w = tid >> 6, lane = tid & 63;
    int lr = lane >> 4, lc = lane & 15;
    int wr = w >> 1, wc = w & 1;
    int row0 = by * 128, col0 = bx * 128;

    f32x4 acc[4][4];
#pragma unroll
    for (int mf = 0; mf < 4; ++mf)
#pragma unroll
        for (int nf = 0; nf < 4; ++nf) acc[mf][nf] = (f32x4){0.f, 0.f, 0.f, 0.f};

    auto stageg = [&](int buf, int k0) {
#pragma unroll
        for (int j = 0; j < 2; ++j) {
            int idx = j * 256 + tid;
            int r = idx >> 2, c = (idx & 3) * 8;
            gl16(A + (size_t)(row0 + r) * K + k0 + c, &sm[buf * 8192 + idx * 8]);
            gl16(Bw + (size_t)(col0 + r) * K + k0 + c, &sm[buf * 8192 + 4096 + idx * 8]);
        }
    };

    stageg(0, 0);
    stageg(1, 32);
    asm volatile("s_waitcnt vmcnt(0)" ::: "memory");
    __builtin_amdgcn_s_barrier();

    for (int k0 = 0; k0 < K; k0 += 64) {
        int ps = (k0 >> 6) & 1;
        bool st = (k0 + 64 < K);
        if (st) {
            stageg((ps ^ 1) * 2, k0 + 64);
            stageg((ps ^ 1) * 2 + 1, k0 + 96);
        }
#pragma unroll
        for (int s = 0; s < 2; ++s) {
            const ushort_t* As = &sm[(ps * 2 + s) * 8192];
            const ushort_t* Bs = As + 4096;
            bf16x8 af[4], bfr[4];
#pragma unroll
            for (int mf = 0; mf < 4; ++mf)
                af[mf] = *(const bf16x8*)&As[(wr * 64 + mf * 16 + lc) * 32 + 8 * lr];
#pragma unroll
            for (int nf = 0; nf < 4; ++nf)
                bfr[nf] = *(const bf16x8*)&Bs[(wc * 64 + nf * 16 + lc) * 32 + 8 * lr];
            __builtin_amdgcn_s_setprio(1);
#pragma unroll
            for (int mf = 0; mf < 4; ++mf)
#pragma unroll
                for (int nf = 0; nf < 4; ++nf)
                    acc[mf][nf] = mfma16(af[mf], bfr[nf], acc[mf][nf]);
            __builtin_amdgcn_s_setprio(0);
        }
        asm volatile("s_waitcnt vmcnt(0)" ::: "memory");
        __builtin_amdgcn_s_barrier();
    }

    if (bx < 16) {
        // ---- Q / K epilogue with RoPE ----
        const int typ = bx >> 3;                 // 0 = Q, 1 = K
        ushort_t* dstb = typ ? Kr : Qr;
#pragma unroll
        for (int nf = 0; nf < 4; ++nf) {
            int fullc = col0 + wc * 64 + nf * 16 + lc;
            int gc = fullc & 1023;
            int h = gc >> 6;
            int d2 = (gc & 63) >> 1;
            int odd = gc & 1;
            float bv = bias[fullc];
#pragma unroll
            for (int mf = 0; mf < 4; ++mf)
#pragma unroll
                for (int r = 0; r < 4; ++r) {
                    int row = row0 + wr * 64 + mf * 16 + 4 * lr + r;
                    int bb = row >> 11, t = row & 2047;
                    float v = acc[mf][nf][r] + bv;
                    float pv = __shfl_xor(v, 1, 64);
                    float cth = cosT[t * 32 + d2], sth = sinT[t * 32 + d2];
                    float o = odd ? (pv * sth + v * cth) : (v * cth - pv * sth);
                    if (typ == 0) o *= SCALE_L2E;
                    int od = odd ? (d2 + 32) : d2;
                    dstb[((size_t)(bb * H_ + h) * T_ + t) * D_ + od] = f2bf(o);
                }
        }
    } else {
        // ---- V epilogue: transpose 128t x 64c half-tiles through LDS ----
        int bb = row0 >> 11;
        int tb = row0 & 2047;
#pragma unroll 1
        for (int half2 = 0; half2 < 2; ++half2) {
            __syncthreads();
            if (wc == half2) {
#pragma unroll
                for (int nf = 0; nf < 4; ++nf) {
                    int fullc = col0 + wc * 64 + nf * 16 + lc;
                    float bv = bias[fullc];
                    int c = nf * 16 + lc;
#pragma unroll
                    for (int mf = 0; mf < 4; ++mf)
#pragma unroll
                        for (int r = 0; r < 4; ++r) {
                            int tl = wr * 64 + mf * 16 + 4 * lr + r;
                            sm[c * 136 + tl] = f2bf(acc[mf][nf][r] + bv);
                        }
                }
            }
            __syncthreads();
            int h = ((bx - 16) << 1) + half2;
#pragma unroll
            for (int it = 0; it < 8; ++it) {
                int idx = it * 256 + tid;
                int c = idx >> 5, j = idx & 31;
                ushort4_t vv = *(const ushort4_t*)&sm[c * 136 + 4 * j];
                *(ushort4_t*)&Vt[((size_t)(bb * H_ + h) * D_ + c) * T_ + tb + 4 * j] = vv;
            }
        }
    }
}

// ---------------- causal flash attention: swapped-QK^T, double-buffered (proven) ----------------
__global__ __launch_bounds__(256) void attn_kernel(const ushort_t* __restrict__ Qr,
                                                   const ushort_t* __restrict__ Kr,
                                                   const ushort_t* __restrict__ Vt,
                                                   ushort_t* __restrict__ attnb) {
    int id = blockIdx.x;
    int x = id & 7;
    int c = (id >> 3) & 31;
    int g = id >> 8;               // 0..3
    int bh = x + 8 * g;
    int qt;
    if (g == 0) qt = c;
    else if (g == 1) qt = 31 - c;
    else if (g == 2) qt = (c + 16) & 31;
    else qt = 31 - ((c + 16) & 31);
    int b = bh >> 4, h = bh & 15;

    const ushort_t* Qp = Qr + (size_t)bh * T_ * D_;
    const ushort_t* Kp = Kr + (size_t)bh * T_ * D_;
    const ushort_t* Vp = Vt + (size_t)bh * D_ * T_;
    int tid = threadIdx.x, w = tid >> 6, lane = tid & 63;
    int lr = lane >> 4, lc = lane & 15;

    __shared__ ushort_t Ks[2][64 * 64];
    __shared__ ushort_t Vs[2][64 * 64];
    __shared__ ushort_t Ps[4][16 * 64];

    bf16x8 ones;
#pragma unroll
    for (int i = 0; i < 8; ++i) ones[i] = (__bf16)1.0f;

    int srow0 = tid >> 3, sch0 = (tid & 7) ^ (srow0 & 7);
    int srow1 = (256 + tid) >> 3, sch1 = (tid & 7) ^ (srow1 & 7);
    const ushort_t* kg0 = Kp + (size_t)srow0 * D_ + sch0 * 8;
    const ushort_t* kg1 = Kp + (size_t)srow1 * D_ + sch1 * 8;
    const ushort_t* vg0 = Vp + (size_t)srow0 * T_ + sch0 * 8;
    const ushort_t* vg1 = Vp + (size_t)srow1 * T_ + sch1 * 8;
    ushort_t* kl0 = &Ks[0][tid * 8];
    ushort_t* kl1 = &Ks[0][(256 + tid) * 8];
    ushort_t* vl0 = &Vs[0][tid * 8];
    ushort_t* vl1 = &Vs[0][(256 + tid) * 8];

    auto stage = [&](int buf, int kt) {
        size_t koff = (size_t)kt * 64 * D_;
        size_t voff = (size_t)kt * 64;
        size_t lb = (size_t)buf * 4096;
        gl16(kg0 + koff, kl0 + lb);
        gl16(vg0 + voff, vl0 + lb);
        gl16(kg1 + koff, kl1 + lb);
        gl16(vg1 + voff, vl1 + lb);
    };

    int qrow = qt * 64 + w * 16 + lc;
    bf16x8 qf0 = *(const bf16x8*)(Qp + (size_t)qrow * D_ + 8 * lr);
    bf16x8 qf1 = *(const bf16x8*)(Qp + (size_t)qrow * D_ + 32 + 8 * lr);

    float m_s = 0.f;
    f32x4 acc[4], acc_l;
#pragma unroll
    for (int f = 0; f < 4; ++f) acc[f] = (f32x4){0.f, 0.f, 0.f, 0.f};
    acc_l = (f32x4){0.f, 0.f, 0.f, 0.f};

    stage(0, 0);
    asm volatile("s_waitcnt vmcnt(0)" ::: "memory");
    __builtin_amdgcn_s_barrier();

    for (int kt = 0; kt <= qt; ++kt) {
        int cur = kt & 1;
        if (kt < qt) stage(cur ^ 1, kt + 1);
        int t0 = kt * 64;

        f32x4 sv[4];
        __builtin_amdgcn_s_setprio(1);
#pragma unroll
        for (int f = 0; f < 4; ++f) {
            sv[f] = (f32x4){-m_s, -m_s, -m_s, -m_s};
            int row = 16 * f + lc;
#pragma unroll
            for (int kk = 0; kk < 2; ++kk) {
                bf16x8 kf = *(const bf16x8*)&Ks[cur][row * 64 + (((lr + 4 * kk) ^ (row & 7)) * 8)];
                sv[f] = mfma16(kf, kk ? qf1 : qf0, sv[f]);
            }
        }
        __builtin_amdgcn_s_setprio(0);

        float lm = -1e30f;
        if (kt == qt) {
#pragma unroll
            for (int f = 0; f < 4; ++f)
#pragma unroll
                for (int r = 0; r < 4; ++r) {
                    int kg = t0 + 16 * f + 4 * lr + r;
                    float v = sv[f][r];
                    v = (kg > qrow) ? -1e30f : v;
                    sv[f][r] = v;
                    lm = fmaxf(lm, v);
                }
        } else {
#pragma unroll
            for (int f = 0; f < 4; ++f)
#pragma unroll
                for (int r = 0; r < 4; ++r)
                    lm = fmaxf(lm, sv[f][r]);
        }

        if (!__all(lm <= 8.0f)) {
            float tm = fmaxf(lm, __shfl_xor(lm, 16, 64));
            tm = fmaxf(tm, __shfl_xor(tm, 32, 64));
            float d = fmaxf(tm, 0.f);
            m_s += d;
            float alpha = fexp2(-d);
            float ar[4];
#pragma unroll
            for (int r = 0; r < 4; ++r) ar[r] = __shfl(alpha, 4 * lr + r, 64);
#pragma unroll
            for (int r = 0; r < 4; ++r) {
                acc_l[r] *= ar[r];
#pragma unroll
                for (int f = 0; f < 4; ++f) acc[f][r] *= ar[r];
            }
#pragma unroll
            for (int f = 0; f < 4; ++f)
#pragma unroll
                for (int r = 0; r < 4; ++r) sv[f][r] -= d;
        }

#pragma unroll
        for (int f = 0; f < 4; ++f) {
            ushort4_t pk;
            pk.x = f2bf(fexp2(sv[f][0]));
            pk.y = f2bf(fexp2(sv[f][1]));
            pk.z = f2bf(fexp2(sv[f][2]));
            pk.w = f2bf(fexp2(sv[f][3]));
            *(ushort4_t*)&Ps[w][lc * 64 + (((4 * f + lr) ^ (lc & 14)) << 2)] = pk;
        }

        __builtin_amdgcn_s_setprio(1);
#pragma unroll
        for (int kk = 0; kk < 2; ++kk) {
            bf16x8 pf = *(const bf16x8*)&Ps[w][lc * 64 + (((8 * kk + 2 * lr) ^ (lc & 14)) << 2)];
            acc_l = mfma16(pf, ones, acc_l);
#pragma unroll
            for (int f = 0; f < 4; ++f) {
                int vrow = 16 * f + lc;
                bf16x8 vfr = *(const bf16x8*)&Vs[cur][vrow * 64 + (((lr + 4 * kk) ^ (vrow & 7)) * 8)];
                acc[f] = mfma16(pf, vfr, acc[f]);
            }
        }
        __builtin_amdgcn_s_setprio(0);

        asm volatile("s_waitcnt vmcnt(0)" ::: "memory");
        __builtin_amdgcn_s_barrier();
    }

    float inv[4];
#pragma unroll
    for (int r = 0; r < 4; ++r) inv[r] = __builtin_amdgcn_rcpf(acc_l[r]);
#pragma unroll
    for (int f = 0; f < 4; ++f)
#pragma unroll
        for (int r = 0; r < 4; ++r) {
            int t = qt * 64 + w * 16 + 4 * lr + r;
            attnb[((size_t)(b * T_ + t)) * 1024 + h * 64 + 16 * f + lc] =
                f2bf(acc[f][r] * inv[r]);
        }
}

extern "C" void kernel_launch(void* const* d_in, const int* in_sizes, int n_in,
                              void* d_out, int out_size, void* d_ws, size_t ws_size,
                              hipStream_t stream) {
    const float* hs     = (const float*)d_in[0];
    const float* cosp   = (const float*)d_in[1];
    const float* sinp   = (const float*)d_in[2];
    const float* qkv_w  = (const float*)d_in[3];
    const float* qkv_b  = (const float*)d_in[4];
    const float* proj_w = (const float*)d_in[5];
    const float* proj_b = (const float*)d_in[6];
    float* out = (float*)d_out;

    const int M = B_ * T_;            // 4096
    ushort_t* Xb     = (ushort_t*)d_ws;
    ushort_t* Wqkvb  = Xb + (size_t)M * C_;
    ushort_t* Wprojb = Wqkvb + (size_t)3072 * C_;
    ushort_t* Qr     = Wprojb + (size_t)C_ * C_;
    ushort_t* Kr     = Qr + (size_t)B_ * H_ * T_ * D_;
    ushort_t* Vt     = Kr + (size_t)B_ * H_ * T_ * D_;
    ushort_t* attnb  = Vt + (size_t)B_ * H_ * T_ * D_;

    cvt3_kernel<<<2048, 256, 0, stream>>>(hs, Xb, M * C_,
                                          qkv_w, Wqkvb, 3072 * C_,
                                          proj_w, Wprojb, C_ * C_);

    gemm_qkv_rope<<<768, 256, 0, stream>>>(Xb, Wqkvb, qkv_b, cosp, sinp, Qr, Kr, Vt);

    attn_kernel<<<1024, 256, 0, stream>>>(Qr, Kr, Vt, attnb);

    gemm_proj<<<512, 256, 0, stream>>>(attnb, Wprojb, proj_b, out, M, C_, C_, 8);
}